// Round 1
// baseline (355.133 us; speedup 1.0000x reference)
//
#include <hip/hip_runtime.h>
#include <hip/hip_bf16.h>

#define NEG_INF_F (-4294967295.0f)  // -(2^32)+1, matches reference padding

typedef __attribute__((ext_vector_type(8))) short bf16x8;   // MFMA A/B frag (4 VGPRs)
typedef __attribute__((ext_vector_type(4))) float f32x4;    // MFMA C/D frag

__device__ __forceinline__ unsigned short f2bf(float x) {
    unsigned u = __float_as_uint(x);
    return (unsigned short)((u + 0x7fffu + ((u >> 16) & 1u)) >> 16);  // RNE
}
__device__ __forceinline__ unsigned f2bf2(float a, float b) {
    __hip_bfloat162 h2 = __float22bfloat162_rn(make_float2(a, b));
    unsigned r; __builtin_memcpy(&r, &h2, 4); return r;
}
union FragU { unsigned u[4]; bf16x8 h; };

// One-pass design: K streamed HBM->regs once; online softmax fuses pool into
// the score loop. LDS ~28 KB; double-buffered K prefetch -> ~167 VGPR,
// 3 blocks/CU, 12 waves/CU.
struct __align__(16) Smem {
    unsigned short Mt[64 * 128];    // 16384 B  M^T bf16 [n][k], swizzle g=(k>>3)^(n&15)
    unsigned short h1s[4][16 * 64]; //  8192 B  per-wave h1 C->A scratch
    float q[128];                   //   512 B
    float cpart[256];               //  1024 B  4 partial chunks of c[n]
    float Om[4][128];               //  2048 B  per-wave pooled partials
    float mw[4], lw[4];             //    32 B  per-wave online-softmax state
};

// 2nd __launch_bounds__ arg = min BLOCKS/CU on this toolchain (R3 evidence):
// (256,3) -> 12 waves/CU -> VGPR cap 170.
__global__ __launch_bounds__(256, 3)
void attn_fused(const float* __restrict__ Q,    // [2048,128]
                const float* __restrict__ Kg,   // [2048,200,128]
                const int*   __restrict__ kid,  // [2048,200]
                const float* __restrict__ W1,   // [512,64]
                const float* __restrict__ b1,   // [64]
                const float* __restrict__ W2,   // [64,32]
                const float* __restrict__ b2,   // [32]
                const float* __restrict__ W3,   // [32,1]
                const float* __restrict__ b3,   // [1]
                float* __restrict__ out)        // [2048,128]
{
    __shared__ Smem sm;
    const int b    = blockIdx.x;
    const int tid  = threadIdx.x;
    const int wave = tid >> 6;
    const int lane = tid & 63;
    const int l15  = lane & 15;
    const int quad = lane >> 4;

    const float* kbase   = Kg + (size_t)b * 25600;
    const int    kidbase = b * 200;

    // Double-buffered K tile registers (2 x 32 floats) + kid per slot.
    float4 kA[2][4], kB[2][4];
    int kidv[2];

#define PREFETCH_K(SLOT, TILE) do {                                             \
        const int t2_  = (TILE) * 16 + l15;                                     \
        const int tr2_ = min(t2_, 199);                                         \
        const float* kr_ = kbase + tr2_ * 128 + quad * 8;                       \
        _Pragma("unroll")                                                       \
        for (int ks_ = 0; ks_ < 4; ++ks_) {                                     \
            kA[SLOT][ks_] = *reinterpret_cast<const float4*>(kr_ + ks_ * 32);   \
            kB[SLOT][ks_] = *reinterpret_cast<const float4*>(kr_ + ks_ * 32 + 4);\
        }                                                                       \
        kidv[SLOT] = kid[kidbase + tr2_];                                       \
    } while (0)

    // Issue first K tile (deep HBM miss) before ALL prologue work so its
    // latency hides under the M-build.
    PREFETCH_K(0, wave);

    if (tid < 128) sm.q[tid] = Q[b * 128 + tid];

    // W2 B-frags + layer-3 consts (global L2-hot, no LDS dependency)
    bf16x8 W2f[2][2];
    #pragma unroll
    for (int ks = 0; ks < 2; ++ks) {
        #pragma unroll
        for (int nt = 0; nt < 2; ++nt) {
            const int n = nt * 16 + l15;
            const int kb = ks * 32 + quad * 8;
            bf16x8 f;
            #pragma unroll
            for (int j = 0; j < 8; ++j) f[j] = (short)f2bf(W2[(kb + j) * 32 + n]);
            W2f[ks][nt] = f;
        }
    }
    const float w3a = W3[l15],  w3b = W3[16 + l15];
    const float b2a = b2[l15],  b2b = b2[16 + l15];
    const float b3v = b3[0];
    __syncthreads();

    // ---- cooperative M build: M[k][n] = (W1k-W1d)[k][n] + q[k]*W1p[k][n] ----
    // stored transposed Mt[n][k], bf16, granule swizzle g=(k>>3)^(n&15).
    {
        const int n  = tid & 63;
        const int ko = (tid >> 6) * 2;
        #pragma unroll
        for (int i = 0; i < 16; ++i) {
            const int k = i * 8 + ko;
            const float v0 = (W1[(128 + k) * 64 + n] - W1[(256 + k) * 64 + n])
                           + sm.q[k] * W1[(384 + k) * 64 + n];
            const float v1 = (W1[(129 + k) * 64 + n] - W1[(257 + k) * 64 + n])
                           + sm.q[k + 1] * W1[(385 + k) * 64 + n];
            const int g = (k >> 3) ^ (n & 15);
            *reinterpret_cast<unsigned*>(&sm.Mt[n * 128 + g * 8 + (k & 7)]) = f2bf2(v0, v1);
        }
    }
    // c[n] partials: wave w does 32 k's
    {
        const int n = tid & 63, kc = tid >> 6;
        float acc = (kc == 0) ? b1[n] : 0.0f;
        #pragma unroll 4
        for (int i = 0; i < 32; ++i) {
            const int k = kc * 32 + i;
            acc += sm.q[k] * (W1[k * 64 + n] + W1[(256 + k) * 64 + n]);
        }
        sm.cpart[kc * 64 + n] = acc;
    }
    __syncthreads();

    float cn[4];
    #pragma unroll
    for (int nt = 0; nt < 4; ++nt) {
        const int n = nt * 16 + l15;
        cn[nt] = sm.cpart[n] + sm.cpart[64 + n] + sm.cpart[128 + n] + sm.cpart[192 + n];
    }

    unsigned short* h1w = &sm.h1s[wave][0];
    const f32x4 zero4 = {0.f, 0.f, 0.f, 0.f};

    float O[32];
    #pragma unroll
    for (int i = 0; i < 32; ++i) O[i] = 0.0f;
    float mrun = -__builtin_inff(), lrun = 0.0f;

#define TILE_BODY(CUR, TILE) do {                                               \
    const int t_ = (TILE) * 16 + l15;                                           \
    f32x4 acc_[4] = {zero4, zero4, zero4, zero4};                               \
    _Pragma("unroll")                                                           \
    for (int ks_ = 0; ks_ < 4; ++ks_) {                                         \
        FragU A_;                                                               \
        A_.u[0] = f2bf2(kA[CUR][ks_].x, kA[CUR][ks_].y);                        \
        A_.u[1] = f2bf2(kA[CUR][ks_].z, kA[CUR][ks_].w);                        \
        A_.u[2] = f2bf2(kB[CUR][ks_].x, kB[CUR][ks_].y);                        \
        A_.u[3] = f2bf2(kB[CUR][ks_].z, kB[CUR][ks_].w);                        \
        const int g_ = (ks_ * 4 + quad) ^ l15;                                  \
        _Pragma("unroll")                                                       \
        for (int nt_ = 0; nt_ < 4; ++nt_) {                                     \
            const bf16x8 Bf_ = *reinterpret_cast<const bf16x8*>(                \
                &sm.Mt[(nt_ * 16 + l15) * 128 + g_ * 8]);                       \
            acc_[nt_] = __builtin_amdgcn_mfma_f32_16x16x32_bf16(A_.h, Bf_, acc_[nt_], 0, 0, 0); \
        }                                                                       \
    }                                                                           \
    /* epilogue: + c[n], relu, paired cvt_pk bf16 -> wave-private scratch */    \
    const int m0_ = quad * 4;                                                   \
    _Pragma("unroll")                                                           \
    for (int nt_ = 0; nt_ < 4; ++nt_) {                                         \
        const int n_ = nt_ * 16 + l15;                                          \
        const float h0_ = fmaxf(acc_[nt_][0] + cn[nt_], 0.0f);                  \
        const float h1_ = fmaxf(acc_[nt_][1] + cn[nt_], 0.0f);                  \
        const float h2_ = fmaxf(acc_[nt_][2] + cn[nt_], 0.0f);                  \
        const float h3_ = fmaxf(acc_[nt_][3] + cn[nt_], 0.0f);                  \
        const unsigned p01_ = f2bf2(h0_, h1_);                                  \
        const unsigned p23_ = f2bf2(h2_, h3_);                                  \
        const int nhi_ = n_ >> 3, nlo_ = n_ & 7;                                \
        h1w[(m0_+0)*64 + ((nhi_ ^ ((m0_+0)&7))*8) + nlo_] = (unsigned short)(p01_);       \
        h1w[(m0_+1)*64 + ((nhi_ ^ ((m0_+1)&7))*8) + nlo_] = (unsigned short)(p01_ >> 16); \
        h1w[(m0_+2)*64 + ((nhi_ ^ ((m0_+2)&7))*8) + nlo_] = (unsigned short)(p23_);       \
        h1w[(m0_+3)*64 + ((nhi_ ^ ((m0_+3)&7))*8) + nlo_] = (unsigned short)(p23_ >> 16); \
    }                                                                           \
    /* layer 2: [16,64] @ [64,32] */                                            \
    f32x4 p0_ = zero4, p1_ = zero4;                                             \
    _Pragma("unroll")                                                           \
    for (int ks_ = 0; ks_ < 2; ++ks_) {                                         \
        const int g_ = (ks_ * 4 + quad) ^ (l15 & 7);                            \
        const bf16x8 A2_ = *reinterpret_cast<const bf16x8*>(&h1w[l15 * 64 + g_ * 8]); \
        p0_ = __builtin_amdgcn_mfma_f32_16x16x32_bf16(A2_, W2f[ks_][0], p0_, 0, 0, 0); \
        p1_ = __builtin_amdgcn_mfma_f32_16x16x32_bf16(A2_, W2f[ks_][1], p1_, 0, 0, 0); \
    }                                                                           \
    /* layer 3: relu + dot(W3), reduce over the 16 cols (l15) */                \
    float sv_[4];                                                               \
    _Pragma("unroll")                                                           \
    for (int r_ = 0; r_ < 4; ++r_)                                              \
        sv_[r_] = fmaxf(p0_[r_] + b2a, 0.f) * w3a + fmaxf(p1_[r_] + b2b, 0.f) * w3b; \
    _Pragma("unroll")                                                           \
    for (int off_ = 1; off_ < 16; off_ <<= 1) {                                 \
        _Pragma("unroll")                                                       \
        for (int r_ = 0; r_ < 4; ++r_) sv_[r_] += __shfl_xor(sv_[r_], off_);    \
    }                                                                           \
    const int src_ = (l15 >> 2) * 16;                                           \
    const float s0_ = __shfl(sv_[0], src_), s1_ = __shfl(sv_[1], src_);         \
    const float s2_ = __shfl(sv_[2], src_), s3_ = __shfl(sv_[3], src_);         \
    const int rr_ = l15 & 3;                                                    \
    const float sres_ = (rr_ == 0) ? s0_ : (rr_ == 1) ? s1_ : (rr_ == 2) ? s2_ : s3_; \
    float x_;                                                                   \
    if (t_ < 200) x_ = (kidv[CUR] != 0) ? (sres_ + b3v) : NEG_INF_F;            \
    else          x_ = -__builtin_inff();                                       \
    float tmax_ = x_;                                                           \
    _Pragma("unroll")                                                           \
    for (int off_ = 1; off_ < 16; off_ <<= 1) tmax_ = fmaxf(tmax_, __shfl_xor(tmax_, off_)); \
    const float mnew_ = fmaxf(mrun, tmax_);                                     \
    const float w_ = __expf(x_ - mnew_);                                        \
    float tsum_ = w_;                                                           \
    _Pragma("unroll")                                                           \
    for (int off_ = 1; off_ < 16; off_ <<= 1) tsum_ += __shfl_xor(tsum_, off_); \
    /* wave-uniform branch: scores depend only on l15, so tmax_/mrun are */     \
    /* identical across all 64 lanes -> no divergence. Skip O-rescale when */   \
    /* the running max did not grow (exact, THR=0).                        */   \
    if (tmax_ > mrun) {                                                         \
        const float alpha_ = __expf(mrun - mnew_);                              \
        lrun = fmaf(lrun, alpha_, tsum_);                                       \
        mrun = mnew_;                                                           \
        _Pragma("unroll")                                                       \
        for (int ks_ = 0; ks_ < 4; ++ks_) {                                     \
            O[ks_*8+0] = fmaf(O[ks_*8+0], alpha_, w_ * kA[CUR][ks_].x);         \
            O[ks_*8+1] = fmaf(O[ks_*8+1], alpha_, w_ * kA[CUR][ks_].y);         \
            O[ks_*8+2] = fmaf(O[ks_*8+2], alpha_, w_ * kA[CUR][ks_].z);         \
            O[ks_*8+3] = fmaf(O[ks_*8+3], alpha_, w_ * kA[CUR][ks_].w);         \
            O[ks_*8+4] = fmaf(O[ks_*8+4], alpha_, w_ * kB[CUR][ks_].x);         \
            O[ks_*8+5] = fmaf(O[ks_*8+5], alpha_, w_ * kB[CUR][ks_].y);         \
            O[ks_*8+6] = fmaf(O[ks_*8+6], alpha_, w_ * kB[CUR][ks_].z);         \
            O[ks_*8+7] = fmaf(O[ks_*8+7], alpha_, w_ * kB[CUR][ks_].w);         \
        }                                                                       \
    } else {                                                                    \
        lrun += tsum_;                                                          \
        _Pragma("unroll")                                                       \
        for (int ks_ = 0; ks_ < 4; ++ks_) {                                     \
            O[ks_*8+0] = fmaf(w_, kA[CUR][ks_].x, O[ks_*8+0]);                  \
            O[ks_*8+1] = fmaf(w_, kA[CUR][ks_].y, O[ks_*8+1]);                  \
            O[ks_*8+2] = fmaf(w_, kA[CUR][ks_].z, O[ks_*8+2]);                  \
            O[ks_*8+3] = fmaf(w_, kA[CUR][ks_].w, O[ks_*8+3]);                  \
            O[ks_*8+4] = fmaf(w_, kB[CUR][ks_].x, O[ks_*8+4]);                  \
            O[ks_*8+5] = fmaf(w_, kB[CUR][ks_].y, O[ks_*8+5]);                  \
            O[ks_*8+6] = fmaf(w_, kB[CUR][ks_].z, O[ks_*8+6]);                  \
            O[ks_*8+7] = fmaf(w_, kB[CUR][ks_].w, O[ks_*8+7]);                  \
        }                                                                       \
    }                                                                           \
} while (0)

    // ---- static tile schedule (wave w: tiles w, w+4, w+8; wave 0 also 12) ----
    // Prefetch for tile i+1 is issued BEFORE computing tile i: the HBM miss
    // (~900 cyc) hides under the tile body (~MFMA + softmax chain).
    PREFETCH_K(1, wave + 4);            // tiles 4..7, always valid
    TILE_BODY(0, wave);
    PREFETCH_K(0, wave + 8);            // tiles 8..11, always valid
    TILE_BODY(1, wave + 4);
    if (wave == 0) PREFETCH_K(1, 12);   // tail tile, wave 0 only
    TILE_BODY(0, wave + 8);
    if (wave == 0) TILE_BODY(1, 12);

#undef TILE_BODY
#undef PREFETCH_K

    // intra-wave reduce of O over l15 (each quad owns cols quad*8+ks*32..+7)
    #pragma unroll
    for (int off = 1; off < 16; off <<= 1) {
        #pragma unroll
        for (int i = 0; i < 32; ++i) O[i] += __shfl_xor(O[i], off);
    }
    if (l15 == 0) {
        #pragma unroll
        for (int ks = 0; ks < 4; ++ks) {
            *reinterpret_cast<float4*>(&sm.Om[wave][ks * 32 + quad * 8]) =
                make_float4(O[ks*8+0], O[ks*8+1], O[ks*8+2], O[ks*8+3]);
            *reinterpret_cast<float4*>(&sm.Om[wave][ks * 32 + quad * 8 + 4]) =
                make_float4(O[ks*8+4], O[ks*8+5], O[ks*8+6], O[ks*8+7]);
        }
    }
    if (lane == 0) { sm.mw[wave] = mrun; sm.lw[wave] = lrun; }
    __syncthreads();

    // ---- merge 4 waves' online states, normalize, store ----
    if (tid < 128) {
        const float M = fmaxf(fmaxf(sm.mw[0], sm.mw[1]), fmaxf(sm.mw[2], sm.mw[3]));
        float den = 0.f, val = 0.f;
        #pragma unroll
        for (int w = 0; w < 4; ++w) {
            const float a = __expf(sm.mw[w] - M);
            den += sm.lw[w] * a;
            val += sm.Om[w][tid] * a;
        }
        out[(size_t)b * 128 + tid] = val / (den * 200.0f);  // softmax norm + mean(/T)
    }
}

extern "C" void kernel_launch(void* const* d_in, const int* in_sizes, int n_in,
                              void* d_out, int out_size, void* d_ws, size_t ws_size,
                              hipStream_t stream) {
    (void)in_sizes; (void)n_in; (void)out_size; (void)d_ws; (void)ws_size;
    attn_fused<<<dim3(2048), dim3(256), 0, stream>>>(
        (const float*)d_in[0], (const float*)d_in[1], (const int*)d_in[2],
        (const float*)d_in[3], (const float*)d_in[4], (const float*)d_in[5],
        (const float*)d_in[6], (const float*)d_in[7], (const float*)d_in[8],
        (float*)d_out);
}